// Round 7
// baseline (92.875 us; speedup 1.0000x reference)
//
#include <hip/hip_runtime.h>
#include <hip/hip_bf16.h>

typedef __bf16 bf16x8 __attribute__((ext_vector_type(8)));
typedef float  f32x4  __attribute__((ext_vector_type(4)));

#define MFMA32(acc, a, b) acc = __builtin_amdgcn_mfma_f32_16x16x32_bf16(a, b, acc, 0, 0, 0)
#define LD4(p) (*(const float4*)(p))

__device__ __forceinline__ bf16x8 cvt8(float4 a, float4 b) {
  bf16x8 r;
  r[0] = (__bf16)a.x; r[1] = (__bf16)a.y; r[2] = (__bf16)a.z; r[3] = (__bf16)a.w;
  r[4] = (__bf16)b.x; r[5] = (__bf16)b.y; r[6] = (__bf16)b.z; r[7] = (__bf16)b.w;
  return r;
}

// DPP helpers: row_ror:N = 0x120|N (16-lane rotate), quad_perm xor2=0x4E, xor1=0xB1.
template <int CTRL>
__device__ __forceinline__ float dpp_mov(float x) {
  int yi = __builtin_amdgcn_update_dpp(0, __builtin_bit_cast(int, x), CTRL, 0xF, 0xF, true);
  return __builtin_bit_cast(float, yi);
}
template <int CTRL>
__device__ __forceinline__ float dpp_fadd(float x) { return x + dpp_mov<CTRL>(x); }
template <int CTRL>
__device__ __forceinline__ float dpp_fmax(float x) { return fmaxf(x, dpp_mov<CTRL>(x)); }

// Packed 16-reg cross-16-lane reduce (validated R6): returns, in lane lr, the
// full 16-lane sum of o[lr]; caller maps lane->dim.
__device__ __forceinline__ float tree16(const float* o, int lr) {
  float q8[8];
#pragma unroll
  for (int t = 0; t < 8; t++) {
    const bool up = (lr & 8);
    float sel = up ? o[t + 8] : o[t];
    float oth = up ? o[t] : o[t + 8];
    q8[t] = sel + dpp_mov<0x128>(oth);
  }
  float q4[4];
#pragma unroll
  for (int t = 0; t < 4; t++) {
    const bool up = (lr & 4);
    float sel = up ? q8[t + 4] : q8[t];
    float oth = up ? q8[t] : q8[t + 4];
    q4[t] = sel + __shfl_xor(oth, 4);
  }
  float q2[2];
#pragma unroll
  for (int t = 0; t < 2; t++) {
    const bool up = (lr & 2);
    float sel = up ? q4[t + 2] : q4[t];
    float oth = up ? q4[t] : q4[t + 2];
    q2[t] = sel + dpp_mov<0x4E>(oth);
  }
  const bool up = (lr & 1);
  float sel = up ? q2[1] : q2[0];
  float oth = up ? q2[0] : q2[1];
  return sel + dpp_mov<0xB1>(oth);
}

// W1frag [ks=4][mt=4][lane][j=8] = W1[ks*32+(lane>>4)*8+j][mt*16+(lane&15)]
// W2frag [ks2=2][mt2=4][lane][j=8] = W2[rho][mt2*16+(lane&15)],
//   rho(ks2,g,j) = (ks2*2+(j>>2))*16 + g*4 + (j&3) — matches in-register hb layout.
__global__ void prep_frags(const float* __restrict__ W1,
                           const float* __restrict__ W2,
                           __bf16* __restrict__ wf) {
  int idx = blockIdx.x * 256 + threadIdx.x;
  if (idx < 8192) {
    int j = idx & 7, lane = (idx >> 3) & 63, mt = (idx >> 9) & 3, ks = idx >> 11;
    int i = ks * 32 + ((lane >> 4) << 3) + j;
    int col = mt * 16 + (lane & 15);
    wf[idx] = (__bf16)W1[i * 64 + col];
  } else if (idx < 12288) {
    int t = idx - 8192;
    int j = t & 7, lane = (t >> 3) & 63, mt2 = (t >> 9) & 3, ks2 = (t >> 11) & 1;
    int g = (lane >> 4) & 3;
    int rho = (ks2 * 2 + (j >> 2)) * 16 + g * 4 + (j & 3);
    wf[idx] = (__bf16)W2[rho * 64 + mt2 * 16 + (lane & 15)];
  }
}

// Bucket nodes by degree. deg==0 handled here (copy own embedding).
// Lists are append-ordered by atomics (order varies, per-node result doesn't).
__global__ void partition(const int* __restrict__ nd, const int* __restrict__ vn,
                          const float* __restrict__ emb, float* __restrict__ out,
                          int* __restrict__ l0, int* __restrict__ l1,
                          int* __restrict__ cnt, int N) {
  int t = blockIdx.x * 256 + threadIdx.x;
  if (t >= N) return;
  int d = nd[t];
  if (d == 0) {
    const float4* s = (const float4*)(emb + (long)vn[t] * 64);
    float4* dst = (float4*)(out + (long)t * 64);
#pragma unroll
    for (int i = 0; i < 16; i++) dst[i] = s[i];
  } else if (d <= 16) {
    l0[atomicAdd(&cnt[0], 1)] = t;
  } else {
    l1[atomicAdd(&cnt[1], 1)] = t;
  }
}

// Work items: [0, npair) = pairs of deg<=16 nodes (tile0 = A, tile1 = B);
// [npair, npair+nS) = single deg>16 nodes (tile0 = nb 0..15, tile1 = 16..31).
// 512 thr = 8 waves/block, one item per wave-iteration. No launch-bounds min
// (R3/R4/R6: extra register pressure converts 1:1 into lost waves).
__global__ __launch_bounds__(512) void graph_agg(
    const float* __restrict__ emb,
    const float* __restrict__ b1g, const float* __restrict__ b2g,
    const float* __restrict__ w3g, const float* __restrict__ b3g,
    const int* __restrict__ vn, const int* __restrict__ ni,
    const int* __restrict__ nd,
    const __bf16* __restrict__ wf,
    const int* __restrict__ l0, const int* __restrict__ l1,
    const int* __restrict__ cnt,
    float* __restrict__ out, int N) {
  __shared__ __align__(16) unsigned char smem[25344];

  {
    const uint4* src = (const uint4*)wf;
    uint4* dst = (uint4*)smem;
#pragma unroll
    for (int i = 0; i < 3; i++) dst[threadIdx.x + i * 512] = src[threadIdx.x + i * 512];
    int t = threadIdx.x;
    if (t < 64) {
      ((float*)(smem + 24576))[t] = b1g[t];
      ((float*)(smem + 24832))[t] = b2g[t];
      ((float*)(smem + 25088))[t] = w3g[t];
    }
  }
  __syncthreads();

  const __bf16* w1f = (const __bf16*)smem;
  const __bf16* w2f = (const __bf16*)(smem + 16384);
  const int wid = threadIdx.x >> 6;
  const int l   = threadIdx.x & 63;
  const int g   = l >> 4;
  const int lr  = l & 15;
  const float b3v = b3g[0];

  const int nP = cnt[0];            // # deg 1..16 nodes
  const int nS = cnt[1];            // # deg>16 nodes
  const int npair = (nP + 1) >> 1;
  const int total = npair + nS;

  const int gw = blockIdx.x * 8 + wid;
  const int nwav = gridDim.x * 8;
  int item = gw;
  if (item >= total) return;

#define LOADDESC(IT, O0_, O1_, C0_, C1_, D0_, D1_, J0_, J1_) do {            \
    if ((IT) < npair) {                                                      \
      int a_ = l0[2 * (IT)];                                                 \
      int b_ = (2 * (IT) + 1 < nP) ? l0[2 * (IT) + 1] : a_;                  \
      O0_ = a_; O1_ = b_; C0_ = vn[a_]; C1_ = vn[b_];                        \
      D0_ = nd[a_]; D1_ = nd[b_];                                            \
      J0_ = ni[(long)a_ * 32 + lr]; J1_ = ni[(long)b_ * 32 + lr];            \
    } else {                                                                 \
      int a_ = l1[(IT) - npair];                                             \
      O0_ = a_; O1_ = a_; C0_ = vn[a_]; C1_ = C0_;                           \
      D0_ = nd[a_]; D1_ = D0_;                                               \
      J0_ = ni[(long)a_ * 32 + lr]; J1_ = ni[(long)a_ * 32 + 16 + lr];       \
    } } while (0)

  int O0, O1, C0, C1, D0, D1, J0, J1;
  LOADDESC(item, O0, O1, C0, C1, D0, D1, J0, J1);

  for (; item < total; item += nwav) {
    const bool isPair = item < npair;

    // ---- gather (no zero-masking: pad lanes clamp to center row; their
    //      scores are masked and att=0, so garbage cannot propagate) ----
    const int thr  = isPair ? lr : 16 + lr;
    const int idx0 = (lr  < D0) ? J0 : C0;     // single: always J0 (D0>16)
    const int idx1 = (thr < D1) ? J1 : C1;
    const float* p0 = emb + (long)idx0 * 64 + g * 8;
    const float* p1 = emb + (long)idx1 * 64 + g * 8;
    const float* qa = emb + (long)C0 * 64 + g * 8;
    const float* qb = emb + (long)C1 * 64 + g * 8;
    float4 e0a = LD4(p0), e0b = LD4(p0 + 4), e0c = LD4(p0 + 32), e0d = LD4(p0 + 36);
    float4 e1a = LD4(p1), e1b = LD4(p1 + 4), e1c = LD4(p1 + 32), e1d = LD4(p1 + 36);
    float4 ua0 = LD4(qa), ua1 = LD4(qa + 4), ua2 = LD4(qa + 32), ua3 = LD4(qa + 36);
    float4 ub0 = LD4(qb), ub1 = LD4(qb + 4), ub2 = LD4(qb + 32), ub3 = LD4(qb + 36);
    bf16x8 ef00 = cvt8(e0a, e0b), ef01 = cvt8(e0c, e0d);
    bf16x8 ef10 = cvt8(e1a, e1b), ef11 = cvt8(e1c, e1d);
    bf16x8 ufa0 = cvt8(ua0, ua1), ufa1 = cvt8(ua2, ua3);
    bf16x8 ufb0 = cvt8(ub0, ub1), ufb1 = cvt8(ub2, ub3);

    int boff = 24576;
    asm volatile("" : "+v"(boff));  // opaque: keep bias reads in LDS, not regs
    const unsigned char* bb = smem + boff;

    // ---- layer 1: both nt tiles always live (pair: A|B, single: nb lo|hi) ----
    f32x4 acc1[4][2];
#pragma unroll
    for (int mt = 0; mt < 4; mt++) {
      f32x4 bv = *(const f32x4*)(bb + (mt * 16 + g * 4) * 4);
      acc1[mt][0] = bv; acc1[mt][1] = bv;
    }
    const bf16x8 xb0s[4] = {ef00, ef01, ufa0, ufa1};
    const bf16x8 xb1s[4] = {ef10, ef11, ufb0, ufb1};
#pragma unroll
    for (int ks = 0; ks < 4; ks++) {
#pragma unroll
      for (int mt = 0; mt < 4; mt++) {
        bf16x8 wa = *(const bf16x8*)(w1f + ((ks * 4 + mt) * 64 + l) * 8);
        MFMA32(acc1[mt][0], wa, xb0s[ks]);
        MFMA32(acc1[mt][1], wa, xb1s[ks]);
      }
    }

    // ---- relu -> layer-2 B-frags (permuted k-axis, in-register) ----
    bf16x8 hb[2][2];
#pragma unroll
    for (int ks2 = 0; ks2 < 2; ks2++)
#pragma unroll
      for (int nt = 0; nt < 2; nt++) {
        bf16x8 v;
#pragma unroll
        for (int j = 0; j < 8; j++) {
          const int mt = ks2 * 2 + (j >> 2), r = j & 3;
          v[j] = (__bf16)fmaxf(acc1[mt][nt][r], 0.f);
        }
        hb[ks2][nt] = v;
      }

    // ---- layer 2 ----
    f32x4 acc2[4][2];
#pragma unroll
    for (int mt2 = 0; mt2 < 4; mt2++) {
      f32x4 bv = *(const f32x4*)(bb + 256 + (mt2 * 16 + g * 4) * 4);
      acc2[mt2][0] = bv; acc2[mt2][1] = bv;
    }
#pragma unroll
    for (int ks2 = 0; ks2 < 2; ks2++)
#pragma unroll
      for (int mt2 = 0; mt2 < 4; mt2++) {
        bf16x8 wa = *(const bf16x8*)(w2f + ((ks2 * 4 + mt2) * 64 + l) * 8);
        MFMA32(acc2[mt2][0], wa, hb[ks2][0]);
        MFMA32(acc2[mt2][1], wa, hb[ks2][1]);
      }

    // ---- prefetch next descriptor (3-level chain hides under score/output) ----
    int P0, P1, Q0, Q1, E0, E1, K0, K1;
    {
      int nit = item + nwav; if (nit >= total) nit = item;
      LOADDESC(nit, P0, P1, Q0, Q1, E0, E1, K0, K1);
    }

    // ---- scores ----
    float sv0 = 0.f, sv1 = 0.f;
#pragma unroll
    for (int mt2 = 0; mt2 < 4; mt2++) {
      f32x4 wv = *(const f32x4*)(bb + 512 + (mt2 * 16 + g * 4) * 4);
#pragma unroll
      for (int r = 0; r < 4; r++) {
        sv0 += fmaxf(acc2[mt2][0][r], 0.f) * wv[r];
        sv1 += fmaxf(acc2[mt2][1][r], 0.f) * wv[r];
      }
    }
    sv0 += __shfl_xor(sv0, 16); sv0 += __shfl_xor(sv0, 32);
    sv1 += __shfl_xor(sv1, 16); sv1 += __shfl_xor(sv1, 32);

    const bool v0 = (lr  < D0);
    const bool v1 = (thr < D1);
    sv0 = v0 ? (sv0 + b3v) : -1e30f;
    sv1 = v1 ? (sv1 + b3v) : -1e30f;

    // ---- softmax: per-tile reduce; joined for single-node items ----
    float mxA = sv0, mxB = sv1;
    mxA = dpp_fmax<0x128>(mxA); mxB = dpp_fmax<0x128>(mxB);
    mxA = dpp_fmax<0x124>(mxA); mxB = dpp_fmax<0x124>(mxB);
    mxA = dpp_fmax<0x122>(mxA); mxB = dpp_fmax<0x122>(mxB);
    mxA = dpp_fmax<0x121>(mxA); mxB = dpp_fmax<0x121>(mxB);
    if (!isPair) { float mj = fmaxf(mxA, mxB); mxA = mj; mxB = mj; }

    float pA = v0 ? __expf(sv0 - mxA) : 0.f;
    float pB = v1 ? __expf(sv1 - mxB) : 0.f;
    float sA = pA, sB = pB;
    sA = dpp_fadd<0x128>(sA); sB = dpp_fadd<0x128>(sB);
    sA = dpp_fadd<0x124>(sA); sB = dpp_fadd<0x124>(sB);
    sA = dpp_fadd<0x122>(sA); sB = dpp_fadd<0x122>(sB);
    sA = dpp_fadd<0x121>(sA); sB = dpp_fadd<0x121>(sB);
    if (!isPair) { float sj = sA + sB; sA = sj; sB = sj; }
    const float aA = pA / sA;
    const float aB = pB / sB;

    // ---- output einsum ----
    float oA[16], oB[16];
#pragma unroll
    for (int j = 0; j < 8; j++) {
      oA[j]     = aA * (float)ef00[j];
      oA[8 + j] = aA * (float)ef01[j];
      oB[j]     = aB * (float)ef10[j];
      oB[8 + j] = aB * (float)ef11[j];
    }
    const int dim = ((lr >> 3) << 5) + g * 8 + (lr & 7);
    if (isPair) {
      float rA = tree16(oA, lr);
      float rB = tree16(oB, lr);
      out[(long)O0 * 64 + dim] = rA;
      out[(long)O1 * 64 + dim] = rB;
    } else {
#pragma unroll
      for (int t = 0; t < 16; t++) oA[t] += oB[t];
      out[(long)O0 * 64 + dim] = tree16(oA, lr);
    }

    O0 = P0; O1 = P1; C0 = Q0; C1 = Q1; D0 = E0; D1 = E1; J0 = K0; J1 = K1;
  }
#undef LOADDESC
}

extern "C" void kernel_launch(void* const* d_in, const int* in_sizes, int n_in,
                              void* d_out, int out_size, void* d_ws, size_t ws_size,
                              hipStream_t stream) {
  const float* emb = (const float*)d_in[0];
  const float* W1  = (const float*)d_in[1];
  const float* b1  = (const float*)d_in[2];
  const float* W2  = (const float*)d_in[3];
  const float* b2  = (const float*)d_in[4];
  const float* w3  = (const float*)d_in[5];
  const float* b3  = (const float*)d_in[6];
  const int* vn = (const int*)d_in[7];
  const int* ni = (const int*)d_in[8];
  const int* nd = (const int*)d_in[9];
  float* out = (float*)d_out;
  const int N = in_sizes[7];

  char* wsb = (char*)d_ws;
  __bf16* wf = (__bf16*)wsb;                 // 24576 B
  int* cnt = (int*)(wsb + 24576);            // 2 ints
  int* lst0 = (int*)(wsb + 24584);           // N ints
  int* lst1 = lst0 + N;                      // N ints

  hipMemsetAsync(cnt, 0, 8, stream);
  prep_frags<<<48, 256, 0, stream>>>(W1, W2, wf);
  partition<<<(N + 255) / 256, 256, 0, stream>>>(nd, vn, emb, out, lst0, lst1, cnt, N);
  graph_agg<<<1024, 512, 0, stream>>>(emb, b1, b2, w3, b3, vn, ni, nd, wf,
                                      lst0, lst1, cnt, out, N);
}